// Round 7
// baseline (44.497 us; speedup 1.0000x reference)
//
#include <hip/hip_runtime.h>
#include <math.h>

// Router: B=4, S=8192, D=1024, E=64, TOP_K=2 (all fp32)
// Output layout (fp32, concatenated flat):
//   [0,       65536)   top_k_probs   [4,8192,2]
//   [65536,   131072)  selected_experts (as float) [4,8192,2]
//   [131072,  2228224) router_logits [4,8192,64]
//
// R7 = R6 (fp32-exact 3-level bf16-split MFMA, LDS-staged W', validated)
// with the barrier restructured T4-style:
//   - __syncthreads() (drains vmcnt(0) incl. A prefetch) replaced by
//     s_waitcnt vmcnt(2) + raw s_barrier: only the wave's 3 W-DMAs must
//     retire at the barrier (cross-wave LDS publication); A register
//     prefetch loads stay in flight across it.
//   - A prefetch deepened to 2 chunks (ring of 3, statically indexed via
//     full unroll) so A-load latency gets ~2 chunk-periods of cover.
// Issue order per chunk: [DMA x3, A(t+2) x2] -> vmcnt(2) retires exactly
// the DMAs (vmcnt is oldest-first, m135). DMA(t+1) writes buf((t+1)&1),
// same-iter reads use buf(t&1): disjoint, so no read/write race even if
// the STAGE drifts to just before s_barrier.

typedef __attribute__((ext_vector_type(8))) short bf16x8;
typedef __attribute__((ext_vector_type(4))) float f32x4;

static constexpr int TOKENS = 32768;
static constexpr int DDIM   = 1024;
static constexpr int NEXP   = 64;
static constexpr size_t OFF_EXP = 65536;
static constexpr size_t OFF_LOG = 131072;

// ---- W 3-level split + fragment-order permute (validated R4/R5/R6) ----
// element (e,k): tile n=e>>4, chunk c=k>>5, lane=(e&15)+16*((k&31)>>3), j=k&7
// dst (shorts) = ((c*4+n)*64 + lane)*8 + j
__global__ void w_split3_kernel(const float* __restrict__ w,
                                short* __restrict__ w1,
                                short* __restrict__ w2,
                                short* __restrict__ w3) {
    int idx = blockIdx.x * blockDim.x + threadIdx.x;
    for (int i = idx; i < NEXP * DDIM; i += gridDim.x * blockDim.x) {
        int e = i >> 10, k = i & 1023;
        float f = w[i];
        unsigned u1 = __float_as_uint(f);
        float f1 = __uint_as_float(u1 & 0xffff0000u);
        float r1 = f - f1;
        unsigned u2 = __float_as_uint(r1);
        float f2 = __uint_as_float(u2 & 0xffff0000u);
        float r2 = r1 - f2;
        unsigned u3 = __float_as_uint(r2);
        int n = e >> 4, c = k >> 5;
        int lane = (e & 15) + ((k & 31) >> 3) * 16;
        int j = k & 7;
        size_t dst = ((size_t)(c * 4 + n) * 64 + lane) * 8 + j;
        w1[dst] = (short)(u1 >> 16);
        w2[dst] = (short)(u2 >> 16);
        w3[dst] = (short)(u3 >> 16);
    }
}

__device__ inline void split8(float4 a, float4 b,
                              bf16x8& o1, bf16x8& o2, bf16x8& o3) {
    float f[8] = {a.x, a.y, a.z, a.w, b.x, b.y, b.z, b.w};
#pragma unroll
    for (int j = 0; j < 8; ++j) {
        unsigned u1 = __float_as_uint(f[j]);
        float f1 = __uint_as_float(u1 & 0xffff0000u);
        float r1 = f[j] - f1;
        unsigned u2 = __float_as_uint(r1);
        float f2 = __uint_as_float(u2 & 0xffff0000u);
        float r2 = r1 - f2;
        o1[j] = (short)(u1 >> 16);
        o2[j] = (short)(u2 >> 16);
        o3[j] = (short)(__float_as_uint(r2) >> 16);
    }
}

// global->LDS DMA, 16B/lane. LDS dest = wave-uniform base + lane*16 (HW);
// global src is per-lane.
typedef const __attribute__((address_space(1))) unsigned int* gas1_t;
typedef __attribute__((address_space(3))) unsigned int* las3_t;
__device__ inline void stage16(const void* g, void* l) {
    __builtin_amdgcn_global_load_lds((gas1_t)(uintptr_t)g,
                                     (las3_t)(uintptr_t)l, 16, 0, 0);
}

__global__ __launch_bounds__(512, 4)
void router_mfma_kernel(const float* __restrict__ h,
                        const short* __restrict__ w1,
                        const short* __restrict__ w2,
                        const short* __restrict__ w3,
                        float* __restrict__ out) {
    // [0,24576): buf0, [24576,49152): buf1. Each buf: [khalf][arr][n] x 1KB.
    // Combine phase overlays [0,17408) after the main loop (safe: buf0's
    // last reads are iter 14, all waves are past barrier(14) by then).
    __shared__ alignas(16) char smem[49152];
    const int tid   = threadIdx.x;
    const int lane  = tid & 63;
    const int wv    = tid >> 6;     // 0..7
    const int khalf = wv & 1;       // K half (0: k<512, 1: k>=512)
    const int mg    = wv >> 1;      // M-tile group 0..3
    const int token0 = blockIdx.x * 64 + mg * 16;
    const int arow  = lane & 15;    // A-frag row (token within tile)
    const int ks    = lane >> 4;    // k slice within chunk

    const float* ap = h + (size_t)(token0 + arow) * DDIM + khalf * 512 + ks * 8;

    // staging assignment: seg = wv*3+i; seg = (a*4+n)*2 + kh
    const short* warr[3] = {w1, w2, w3};
    const char* gsrc[3];
    int ldso[3];
#pragma unroll
    for (int i = 0; i < 3; ++i) {
        int seg = wv * 3 + i;
        int kh = seg & 1;
        int an = seg >> 1;          // 0..11
        int a = an >> 2, n = an & 3;
        gsrc[i] = (const char*)warr[a] + (size_t)(kh * 64 + n) * 1024 + lane * 16;
        ldso[i] = (kh * 12 + a * 4 + n) * 1024;
    }

#define STAGE(bb, cc)                                                      \
    {                                                                      \
        _Pragma("unroll")                                                  \
        for (int i = 0; i < 3; ++i)                                        \
            stage16(gsrc[i] + (size_t)(cc) * 4096,                         \
                    smem + (bb) * 24576 + ldso[i]);                        \
    }

    f32x4 acc[4];
#pragma unroll
    for (int n = 0; n < 4; ++n)
#pragma unroll
        for (int r = 0; r < 4; ++r) acc[n][r] = 0.0f;

    // A-chunk register ring, depth 3. All indices compile-time (full unroll).
    float4 ring[3][2];

    // prologue: issue [DMA(0) x3, A(0) x2, A(1) x2]; retire DMAs -> vmcnt(4)
    STAGE(0, 0);
    ring[0][0] = *reinterpret_cast<const float4*>(ap);
    ring[0][1] = *reinterpret_cast<const float4*>(ap + 4);
    ring[1][0] = *reinterpret_cast<const float4*>(ap + 32);
    ring[1][1] = *reinterpret_cast<const float4*>(ap + 36);
    asm volatile("s_waitcnt vmcnt(4)" ::: "memory");
    __builtin_amdgcn_s_barrier();

#pragma unroll
    for (int t = 0; t < 16; ++t) {
        const int b = t & 1;
        if (t < 15) STAGE(b ^ 1, t + 1);          // [DMA x3] -> buf b^1
        if (t < 14) {                              // [A(t+2) x2]
            ring[(t + 2) % 3][0] =
                *reinterpret_cast<const float4*>(ap + (t + 2) * 32);
            ring[(t + 2) % 3][1] =
                *reinterpret_cast<const float4*>(ap + (t + 2) * 32 + 4);
        }

        bf16x8 A1f, A2f, A3f;
        split8(ring[t % 3][0], ring[t % 3][1], A1f, A2f, A3f);

        const char* wb = smem + b * 24576 + khalf * 12288 + lane * 16;
#pragma unroll
        for (int n = 0; n < 4; ++n) {
            bf16x8 W1v = *reinterpret_cast<const bf16x8*>(wb + n * 1024);
            bf16x8 W2v = *reinterpret_cast<const bf16x8*>(wb + n * 1024 + 4096);
            bf16x8 W3v = *reinterpret_cast<const bf16x8*>(wb + n * 1024 + 8192);
            f32x4 t2 = acc[n];
            t2 = __builtin_amdgcn_mfma_f32_16x16x32_bf16(A3f, W1v, t2, 0, 0, 0);
            t2 = __builtin_amdgcn_mfma_f32_16x16x32_bf16(A1f, W3v, t2, 0, 0, 0);
            t2 = __builtin_amdgcn_mfma_f32_16x16x32_bf16(A2f, W2v, t2, 0, 0, 0);
            t2 = __builtin_amdgcn_mfma_f32_16x16x32_bf16(A2f, W1v, t2, 0, 0, 0);
            t2 = __builtin_amdgcn_mfma_f32_16x16x32_bf16(A1f, W2v, t2, 0, 0, 0);
            t2 = __builtin_amdgcn_mfma_f32_16x16x32_bf16(A1f, W1v, t2, 0, 0, 0);
            acc[n] = t2;
        }

        if (t < 14) {
            // outstanding (oldest first): [DMA(t+1) x3, A(t+2) x2]
            asm volatile("s_waitcnt vmcnt(2)" ::: "memory");
            __builtin_amdgcn_s_barrier();
        } else if (t == 14) {
            // outstanding: [DMA(15) x3] only
            asm volatile("s_waitcnt vmcnt(0)" ::: "memory");
            __builtin_amdgcn_s_barrier();
        }
    }

    // ---- combine K-halves through LDS (overlay region, stride 17 floats) ----
    if (khalf == 1) {
        float* c = (float*)smem + (size_t)(mg * 64 + lane) * 17;
#pragma unroll
        for (int n = 0; n < 4; ++n)
#pragma unroll
            for (int r = 0; r < 4; ++r) c[n * 4 + r] = acc[n][r];
    }
    __syncthreads();
    if (khalf != 0) return;

    {
        const float* c = (const float*)smem + (size_t)(mg * 64 + lane) * 17;
#pragma unroll
        for (int n = 0; n < 4; ++n)
#pragma unroll
            for (int r = 0; r < 4; ++r) acc[n][r] += c[n * 4 + r];
    }

    const int rbase = (lane >> 4) * 4;   // C/D row group (token offset)
    const int col   = lane & 15;         // C/D col (expert within tile)

    // ---- logits ----
#pragma unroll
    for (int n = 0; n < 4; ++n)
#pragma unroll
        for (int r = 0; r < 4; ++r)
            out[OFF_LOG + (size_t)(token0 + rbase + r) * NEXP + n * 16 + col]
                = acc[n][r];

    // ---- softmax + top-2 per token (16-lane groups, xor 1,2,4,8) ----
#pragma unroll
    for (int r = 0; r < 4; ++r) {
        const int token = token0 + rbase + r;
        float mx = fmaxf(fmaxf(acc[0][r], acc[1][r]),
                         fmaxf(acc[2][r], acc[3][r]));
#pragma unroll
        for (int d = 1; d <= 8; d <<= 1) mx = fmaxf(mx, __shfl_xor(mx, d, 64));

        float p[4];
        float s = 0.0f;
#pragma unroll
        for (int n = 0; n < 4; ++n) { p[n] = expf(acc[n][r] - mx); s += p[n]; }
#pragma unroll
        for (int d = 1; d <= 8; d <<= 1) s += __shfl_xor(s, d, 64);

        // local top-2 over n (expert = n*16 + col, ascending; '>' keeps lower)
        float v1 = -INFINITY, v2 = -INFINITY;
        int   i1 = NEXP,      i2 = NEXP;
#pragma unroll
        for (int n = 0; n < 4; ++n) {
            float v = p[n];
            int   ei = n * 16 + col;
            if (v > v1)      { v2 = v1; i2 = i1; v1 = v; i1 = ei; }
            else if (v > v2) { v2 = v;  i2 = ei; }
        }

        // merge across the 16 lanes of the group
#pragma unroll
        for (int d = 1; d <= 8; d <<= 1) {
            float ov1 = __shfl_xor(v1, d, 64);
            float ov2 = __shfl_xor(v2, d, 64);
            int   oi1 = __shfl_xor(i1, d, 64);
            int   oi2 = __shfl_xor(i2, d, 64);
            bool ofirst = (ov1 > v1) || (ov1 == v1 && oi1 < i1);
            float n1, n2; int ni1, ni2;
            if (ofirst) {
                n1 = ov1; ni1 = oi1;
                bool sec = (v1 > ov2) || (v1 == ov2 && i1 < oi2);
                n2 = sec ? v1 : ov2; ni2 = sec ? i1 : oi2;
            } else {
                n1 = v1; ni1 = i1;
                bool sec = (ov1 > v2) || (ov1 == v2 && oi1 < i2);
                n2 = sec ? ov1 : v2; ni2 = sec ? oi1 : i2;
            }
            v1 = n1; i1 = ni1; v2 = n2; i2 = ni2;
        }

        if (col == 0) {
            float t1 = v1 / s;
            float t2 = v2 / s;
            float dn = t1 + t2 + 1e-8f;
            float2 pr; pr.x = t1 / dn; pr.y = t2 / dn;
            *reinterpret_cast<float2*>(out + (size_t)token * 2) = pr;
            float2 ex; ex.x = (float)i1; ex.y = (float)i2;
            *reinterpret_cast<float2*>(out + OFF_EXP + (size_t)token * 2) = ex;
        }
    }
#undef STAGE
}

extern "C" void kernel_launch(void* const* d_in, const int* in_sizes, int n_in,
                              void* d_out, int out_size, void* d_ws, size_t ws_size,
                              hipStream_t stream) {
    const float* h = (const float*)d_in[0];
    const float* w = (const float*)d_in[1];
    float* out = (float*)d_out;
    // d_ws: W1 | W2 | W3, each 65536 shorts = 384 KiB total
    short* w1 = (short*)d_ws;
    short* w2 = w1 + (size_t)NEXP * DDIM;
    short* w3 = w2 + (size_t)NEXP * DDIM;
    hipLaunchKernelGGL(w_split3_kernel, dim3(128), dim3(256), 0, stream, w, w1, w2, w3);
    hipLaunchKernelGGL(router_mfma_kernel, dim3(TOKENS / 64), dim3(512), 0, stream,
                       h, w1, w2, w3, out);
}